// Round 4
// baseline (903.093 us; speedup 1.0000x reference)
//
#include <hip/hip_runtime.h>
#include <cstdint>
#include <cstddef>

// ---------------------------------------------------------------------------
// SlotAttention on MI355X.
//  (1) prepack: bf16 weight images in MFMA B-fragment order; slot_init copy.
//  (2) gemm_kv: x=LN(inputs); [k|v] = x @ [k_w/16 | v_w] via bf16 MFMA.
//      64-token blocks, 512 thr (8 waves), acc[4][4], concurrent K+V scatter.
//  (3) attn R7: grid (32,64); block = 64 tokens/wave x HALF of D (8 dt).
//      accU[8]=32 VGPR, q frags in LDS -> ~5 waves/SIMD (was 3). QK+softmax
//      redundant per half (K bytes x2 — free: R2 ablation showed attn_pv
//      with HALF the bytes ran at identical speed => latency-bound).
//  (4) fuse: 512 thr (8 waves); reduce re-indexed for 32 half-width partials.
// ---------------------------------------------------------------------------

typedef __attribute__((ext_vector_type(8))) short short8;
typedef __attribute__((ext_vector_type(4))) float f32x4;
typedef __attribute__((ext_vector_type(4))) unsigned short us4;
typedef __attribute__((ext_vector_type(8))) unsigned short us8;

#define DEV static __device__ __forceinline__

DEV unsigned short f2bf(float f) {
  union { float f; unsigned int u; } v; v.f = f;
  unsigned int r = v.u + 0x7FFFu + ((v.u >> 16) & 1u);
  return (unsigned short)(r >> 16);
}

DEV f32x4 mfma16(short8 a, short8 b, f32x4 c) {
  return __builtin_amdgcn_mfma_f32_16x16x32_bf16(a, b, c, 0, 0, 0);
}

// ---------------- workspace layout (bytes) ----------------
constexpr size_t O_KF   = 0;                                  // k frags: [64][256 tb][8 dc][64 chunk(pi)][8] bf16
constexpr size_t SZ_KF  = (size_t)64*256*8*64*8*2;            // 128 MB
constexpr size_t O_VF   = O_KF + SZ_KF;                       // v frags: [64][128 c32][16 dt][64][8] bf16
constexpr size_t SZ_VF  = (size_t)64*128*16*64*8*2;           // 128 MB
constexpr size_t O_ACC  = O_VF + SZ_VF;                       // [64][32 part][8 s][128 d] f32 = 8 MB
constexpr size_t SZ_ACC = (size_t)64*32*8*256*4;              // 16 MB reserved
constexpr size_t O_SUM  = O_ACC + SZ_ACC;                     // [64][16][8] f32
constexpr size_t SZ_SUM = (size_t)64*32*8*4;
constexpr size_t O_SL   = O_SUM + SZ_SUM;                     // slots [64][8][256] f32
constexpr size_t SZ_SL  = (size_t)64*8*256*4;
constexpr size_t O_QF   = O_SL + SZ_SL;                       // q frags [64][8 dc][64][8] bf16
constexpr size_t SZ_QF  = (size_t)64*8*64*8*2;
constexpr size_t O_WKV  = O_QF + SZ_QF;                       // [32 ct][8 dc][64][8]
constexpr size_t SZ_WKV = (size_t)32*8*64*8*2;
constexpr size_t O_WQ   = O_WKV + SZ_WKV;                     // [16][8][64][8]
constexpr size_t SZ_WQ  = (size_t)16*8*64*8*2;
constexpr size_t O_WGRU = O_WQ + SZ_WQ;                       // [96][8][64][8] (wi:0-47, wh:48-95)
constexpr size_t SZ_WGRU= (size_t)96*8*64*8*2;
constexpr size_t O_WM1  = O_WGRU + SZ_WGRU;                   // [32][8][64][8]
constexpr size_t SZ_WM1 = (size_t)32*8*64*8*2;
constexpr size_t O_WM2  = O_WM1 + SZ_WM1;                     // [16][16][64][8]
constexpr size_t SZ_WM2 = (size_t)16*16*64*8*2;
constexpr size_t WS_NEED= O_WM2 + SZ_WM2;                     // ~275 MB

// ---------------------------------------------------------------------------
// prepack: weight fragment images + slots init. 544 blocks x 256.
// B-frag convention: lane L holds W[k = dc*32 + (L>>4)*8 + j][col = ct*16 + (L&15)]
// ---------------------------------------------------------------------------
__global__ void prepack(
    const float* __restrict__ kw, const float* __restrict__ qw,
    const float* __restrict__ vw, const float* __restrict__ wi,
    const float* __restrict__ wh, const float* __restrict__ w1,
    const float* __restrict__ w2, const float* __restrict__ slot_init,
    unsigned short* __restrict__ wkv, unsigned short* __restrict__ wq_,
    unsigned short* __restrict__ wgru, unsigned short* __restrict__ wm1,
    unsigned short* __restrict__ wm2, float* __restrict__ slots)
{
  int idx = blockIdx.x * 256 + threadIdx.x;
  if (idx < 16384) {                                    // kv: [32][8][64]
    int ct = idx >> 9, dc = (idx >> 6) & 7, L = idx & 63;
    int col = ct*16 + (L & 15), k0 = dc*32 + ((L>>4)*8);
    if (col < 256) {
      for (int j = 0; j < 8; ++j) wkv[idx*8+j] = f2bf(kw[(size_t)(k0+j)*256 + col] * 0.0625f);
    } else {
      int c = col - 256;
      for (int j = 0; j < 8; ++j) wkv[idx*8+j] = f2bf(vw[(size_t)(k0+j)*256 + c]);
    }
  } else if (idx < 24576) {                             // q: [16][8][64]
    int t = idx - 16384;
    int ct = t >> 9, dc = (t >> 6) & 7, L = t & 63;
    int col = ct*16 + (L & 15), k0 = dc*32 + ((L>>4)*8);
    for (int j = 0; j < 8; ++j) wq_[t*8+j] = f2bf(qw[(size_t)(k0+j)*256 + col]);
  } else if (idx < 73728) {                             // gru: [96][8][64]
    int t = idx - 24576;
    int ct = t >> 9, dc = (t >> 6) & 7, L = t & 63;
    int k0 = dc*32 + ((L>>4)*8);
    const float* W = (ct < 48) ? wi : wh;
    int col = ((ct < 48) ? ct : (ct - 48))*16 + (L & 15);
    for (int j = 0; j < 8; ++j) wgru[t*8+j] = f2bf(W[(size_t)(k0+j)*768 + col]);
  } else if (idx < 90112) {                             // mlp1: [32][8][64]
    int t = idx - 73728;
    int ct = t >> 9, dc = (t >> 6) & 7, L = t & 63;
    int col = ct*16 + (L & 15), k0 = dc*32 + ((L>>4)*8);
    for (int j = 0; j < 8; ++j) wm1[t*8+j] = f2bf(w1[(size_t)(k0+j)*512 + col]);
  } else if (idx < 106496) {                            // mlp2: [16][16][64]
    int t = idx - 90112;
    int ct = t >> 10, dc = (t >> 6) & 15, L = t & 63;
    int col = ct*16 + (L & 15), k0 = dc*32 + ((L>>4)*8);
    for (int j = 0; j < 8; ++j) wm2[t*8+j] = f2bf(w2[(size_t)(k0+j)*256 + col]);
  } else {                                              // slots copy (float4)
    int t = idx - 106496;
    f32x4 v = *(const f32x4*)(slot_init + (size_t)t*4);
    *(f32x4*)(slots + (size_t)t*4) = v;
  }
}

// ---------------------------------------------------------------------------
// gemm_kv: 4096 blocks x 512 thr. Block = 64 tokens x all 512 out cols.
// Wave w owns ct = 4w..4w+3 (64 cols) across 4 token tiles: acc[4][4] = 64
// AGPR (16 waves/CU reg cap), each B-frag load feeds 4 MFMAs.
// Phases: LN-stage | MFMA | concurrent K+V scatter | coalesced store.
// K image chunk permutation: pi = o1*32 | r*8 | o0*4 | q  (conflict-free)
// ---------------------------------------------------------------------------
__global__ __launch_bounds__(512, 4) void gemm_kv(
    const float* __restrict__ x, const float* __restrict__ lng,
    const float* __restrict__ lnb, const unsigned short* __restrict__ wkv,
    unsigned short* __restrict__ kfr, unsigned short* __restrict__ vfr)
{
  // 64 KB: A-tile 64x264 shorts (33.8 KB), then reused as
  //        K img shorts [0,16384) + V img shorts [16384,32768)
  __shared__ unsigned short smem[32768];
  int tid = threadIdx.x, w = tid >> 6, L = tid & 63;
  int m16 = L & 15, q = L >> 4;
  int blk = blockIdx.x;
  int b = blk >> 6;
  int n0 = (blk & 63) << 6;

  { // fused LN + stage bf16 A tile. wave w: rows w*8..w*8+7; 8 thr/row
    int r = (w << 3) + (L & 7), t8 = L >> 3;
    const float* xr = x + ((size_t)((b << 12) + n0 + r) << 8) + (t8 << 5);
    float xv[32];
    float s = 0.f, s2 = 0.f;
#pragma unroll
    for (int i = 0; i < 8; ++i) {
      f32x4 v = *(const f32x4*)(xr + (i << 2));
#pragma unroll
      for (int jj = 0; jj < 4; ++jj) { float t = v[jj]; xv[i*4+jj] = t; s += t; s2 += t*t; }
    }
    s  += __shfl_xor(s, 8);  s  += __shfl_xor(s, 16);  s  += __shfl_xor(s, 32);
    s2 += __shfl_xor(s2, 8); s2 += __shfl_xor(s2, 16); s2 += __shfl_xor(s2, 32);
    float mean = s * 0.00390625f;
    float var  = s2 * 0.00390625f - mean * mean;
    float rstd = rsqrtf(fmaxf(var, 0.f) + 1e-5f);
    unsigned short* arow = smem + r * 264 + (t8 << 5);
    const float* gg = lng + (t8 << 5);
    const float* bb = lnb + (t8 << 5);
#pragma unroll
    for (int i = 0; i < 4; ++i) {
      f32x4 g0 = *(const f32x4*)(gg + (i << 3));
      f32x4 g1 = *(const f32x4*)(gg + (i << 3) + 4);
      f32x4 b0 = *(const f32x4*)(bb + (i << 3));
      f32x4 b1 = *(const f32x4*)(bb + (i << 3) + 4);
      us8 pk;
#pragma unroll
      for (int jj = 0; jj < 4; ++jj) {
        pk[jj]     = f2bf((xv[i*8+jj]   - mean) * rstd * g0[jj] + b0[jj]);
        pk[4 + jj] = f2bf((xv[i*8+4+jj] - mean) * rstd * g1[jj] + b1[jj]);
      }
      *(us8*)(arow + (i << 3)) = pk;
    }
  }
  __syncthreads();

  f32x4 acc[4][4];
#pragma unroll
  for (int mt = 0; mt < 4; ++mt)
#pragma unroll
    for (int c = 0; c < 4; ++c) acc[mt][c] = (f32x4){0.f,0.f,0.f,0.f};

#pragma unroll
  for (int dc = 0; dc < 8; ++dc) {
    short8 af[4];
#pragma unroll
    for (int mt = 0; mt < 4; ++mt)
      af[mt] = *(const short8*)(smem + ((mt << 4) + m16) * 264 + dc*32 + q*8);
#pragma unroll
    for (int c = 0; c < 4; ++c) {
      short8 bf = *(const short8*)(wkv + ((((w<<2)+c)*8 + dc)*64 + L) * 8);
#pragma unroll
      for (int mt = 0; mt < 4; ++mt)
        acc[mt][c] = mfma16(af[mt], bf, acc[mt][c]);
    }
  }
  __syncthreads();   // A-tile dead; reuse smem for both images

  if (w < 4) {          // K image: cols 0..255, chunk pos = pi(oct,r,q)
#pragma unroll
    for (int mt = 0; mt < 4; ++mt)
#pragma unroll
      for (int c = 0; c < 4; ++c) {
        int col = (w << 6) + (c << 4) + m16;
        int dc = col >> 5, oct = (col >> 3) & 3, j = col & 7;
        int base = ((mt << 3) + dc)*64 + ((oct >> 1) << 5) + ((oct & 1) << 2) + q;
#pragma unroll
        for (int r = 0; r < 4; ++r)
          smem[(base + (r << 3))*8 + j] = f2bf(acc[mt][c][r]);
      }
  } else {              // V image: cols 256..511 -> d-major (transposed) A-frag
#pragma unroll
    for (int mt = 0; mt < 4; ++mt)
#pragma unroll
      for (int c = 0; c < 4; ++c) {
        int d = ((w - 4) << 6) + (c << 4) + m16;
        int dt = d >> 4;
        int tok = ((mt & 1) << 4) + (q << 2);
        int lp = m16 + ((tok >> 3) << 4), j0 = (q & 1) << 2;
        us4 pk;
#pragma unroll
        for (int r = 0; r < 4; ++r) pk[r] = f2bf(acc[mt][c][r]);
        *(us4*)&smem[16384 + ((mt >> 1) << 13) + ((dt << 6) + lp)*8 + j0] = pk;
      }
  }
  __syncthreads();
  { // store K image (coalesced, 2048 us8)
    size_t kb = (size_t)b*256 + ((blk & 63) << 2);
#pragma unroll
    for (int ii = 0; ii < 4; ++ii) {
      int cix = ii*512 + tid;
      int rt = cix >> 9, dcs = (cix >> 6) & 7, p = cix & 63;
      short8 vv = *(const short8*)(smem + (size_t)cix*8);
      *(short8*)(kfr + (((kb + rt)*8 + dcs)*64 + p)*8) = vv;
    }
    // store V image (coalesced, 2048 us8)
    size_t vb = (size_t)b*128 + ((blk & 63) << 1);
#pragma unroll
    for (int ii = 0; ii < 4; ++ii) {
      int cix = ii*512 + tid;
      int cc = cix >> 10, dt = (cix >> 6) & 15, lp = cix & 63;
      short8 vv = *(const short8*)(smem + 16384 + (size_t)cix*8);
      *(short8*)(vfr + (((vb + cc)*16 + dt)*64 + lp)*8) = vv;
    }
  }
}

// ---------------------------------------------------------------------------
// attn R7: grid (32, 64) x 256. blockIdx.x = {bt 0..15} x {half 0..1}.
// Each block: 4 waves x 64 tokens x 2 chunks, HALF of D (dt = half*8..+7).
// accU[8] (32 VGPR), q frags staged in LDS -> launch_bounds(256,5).
// QK + softmax computed redundantly in both halves (bytes are free: R2).
// K chunks at pi-permuted positions -> base-pointer offset pk*8.
// ---------------------------------------------------------------------------
__global__ __launch_bounds__(256, 5) void attn(
    const unsigned short* __restrict__ kfr,
    const unsigned short* __restrict__ vfr,
    const unsigned short* __restrict__ qfg,
    float* __restrict__ accp, float* __restrict__ sump)
{
  __shared__ float red[4][8][132];
  __shared__ float rsum[4][8];
  __shared__ unsigned short qlds[4096];   // 8 KB: [8 dc][64][8]
  int tid = threadIdx.x, w = tid >> 6, L = tid & 63;
  int slot = L & 15, q = L >> 4;
  int x = blockIdx.x, b = blockIdx.y;
  int bt = x >> 1, half = x & 1;
  int wv = (bt << 2) + w;
  int pk = (L & 32) | ((L & 3) << 3) | ((L & 16) >> 2) | ((L >> 2) & 3);
  const unsigned short* kb = kfr + ((size_t)b << 20) + pk*8;
  const unsigned short* vbp = vfr + ((size_t)b << 20) + (half << 12) + L*8;

  { // stage q fragments (8 KB) once per block
    const unsigned short* qg = qfg + ((size_t)b << 12);
    *(us8*)&qlds[tid*8]        = *(const us8*)(qg + tid*8);
    *(us8*)&qlds[(tid+256)*8]  = *(const us8*)(qg + (tid+256)*8);
  }
  __syncthreads();

  f32x4 accU[8];
#pragma unroll
  for (int dt = 0; dt < 8; ++dt) accU[dt] = (f32x4){0.f,0.f,0.f,0.f};
  float rs = 0.f;

#pragma unroll
  for (int c = 0; c < 2; ++c) {
    int tb0 = (wv << 2) + (c << 1);
    int c32 = (wv << 1) + c;
    const unsigned short* kt = kb + (size_t)tb0 * 4096;
    const unsigned short* vt = vbp + (size_t)c32 * 8192;
    short8 vfA[4];
#pragma unroll
    for (int dt = 0; dt < 4; ++dt)
      vfA[dt] = *(const short8*)(vt + dt*512);
    f32x4 d0 = (f32x4){0.f,0.f,0.f,0.f}, d1 = (f32x4){0.f,0.f,0.f,0.f};
    __builtin_amdgcn_s_setprio(1);
#pragma unroll
    for (int dc = 0; dc < 8; ++dc) {
      short8 k0 = *(const short8*)(kt + dc*512);
      short8 k1 = *(const short8*)(kt + 4096 + dc*512);
      short8 qf = *(const short8*)(qlds + (dc*64 + L)*8);
      d0 = mfma16(k0, qf, d0);
      d1 = mfma16(k1, qf, d1);
    }
    __builtin_amdgcn_s_setprio(0);
    // softmax over 8 slots (dots are O(1): skip max-subtract), +eps
    float p0[4], p1[4];
#pragma unroll
    for (int r = 0; r < 4; ++r) {
      float e = __expf(d0[r]);
      float ss = e;
      ss += __shfl_xor(ss, 1); ss += __shfl_xor(ss, 2); ss += __shfl_xor(ss, 4);
      float pv = (slot < 8) ? (e / ss + 1e-6f) : 0.f;
      rs += pv; p0[r] = pv;
    }
#pragma unroll
    for (int r = 0; r < 4; ++r) {
      float e = __expf(d1[r]);
      float ss = e;
      ss += __shfl_xor(ss, 1); ss += __shfl_xor(ss, 2); ss += __shfl_xor(ss, 4);
      float pv = (slot < 8) ? (e / ss + 1e-6f) : 0.f;
      rs += pv; p1[r] = pv;
    }
    // in-wave transform to B-frag: pb[j] = P[token 8q+j][slot m16]
    short8 pb;
#pragma unroll
    for (int j = 0; j < 8; ++j) {
      int srcl = slot + ((q & 1) << 5) + ((j >> 2) << 4);
      float va = __shfl(p0[j & 3], srcl);
      float vb2 = __shfl(p1[j & 3], srcl);
      pb[j] = (short)f2bf((q >> 1) ? vb2 : va);
    }
    __builtin_amdgcn_s_setprio(1);
#pragma unroll
    for (int dt = 0; dt < 4; ++dt) accU[dt] = mfma16(vfA[dt], pb, accU[dt]);
#pragma unroll
    for (int dt = 4; dt < 8; ++dt) {
      short8 vv = *(const short8*)(vt + dt*512);
      accU[dt] = mfma16(vv, pb, accU[dt]);
    }
    __builtin_amdgcn_s_setprio(0);
  }
  rs += __shfl_xor(rs, 16);
  rs += __shfl_xor(rs, 32);
  if (slot < 8) {
#pragma unroll
    for (int dt = 0; dt < 8; ++dt)
      *(f32x4*)&red[w][slot][dt*16 + (q << 2)] = accU[dt];
  }
  if (L < 8) rsum[w][L] = rs;
  __syncthreads();
  { // block reduction over 4 waves -> one half-width partial per block
    int s = tid >> 5, dp = (tid & 31) << 2;
    f32x4 a0 = (f32x4){0.f,0.f,0.f,0.f};
#pragma unroll
    for (int ww = 0; ww < 4; ++ww)
      a0 += *(const f32x4*)&red[ww][s][dp];
    float* ab = accp + (((size_t)(b << 5) + x)*8 + s)*128 + dp;
    *(f32x4*)ab = a0;
    if (half == 0 && tid < 8)
      sump[(((b << 4) + bt) << 3) + tid] =
          rsum[0][tid] + rsum[1][tid] + rsum[2][tid] + rsum[3][tid];
  }
}

// ---------------------------------------------------------------------------
// fuse: 64 blocks x 512 thr (8 waves, 2 waves/SIMD). mode1: reduce 32
// half-width partials -> updates -> GRU -> LN -> MLP -> residual -> slots
// (+out). Always: pack next-iter q.
// ---------------------------------------------------------------------------
DEV void ln_stats512(const float hpr[16][260], float stats[16][2], int tid) {
  int row = tid >> 5, seg = tid & 31;    // 512 thr = 16 rows x 32 segs x 8 el
  float s = 0.f, s2 = 0.f;
#pragma unroll
  for (int jj = 0; jj < 8; ++jj) { float v = hpr[row][seg*8 + jj]; s += v; s2 += v*v; }
  s  += __shfl_xor(s, 1);  s  += __shfl_xor(s, 2);  s  += __shfl_xor(s, 4);
  s  += __shfl_xor(s, 8);  s  += __shfl_xor(s, 16);
  s2 += __shfl_xor(s2, 1); s2 += __shfl_xor(s2, 2); s2 += __shfl_xor(s2, 4);
  s2 += __shfl_xor(s2, 8); s2 += __shfl_xor(s2, 16);
  if (seg == 0) {
    float mean = s * 0.00390625f;
    float var  = s2 * 0.00390625f - mean*mean;
    stats[row][0] = mean;
    stats[row][1] = rsqrtf(fmaxf(var, 0.f) + 1e-5f);
  }
}

__global__ __launch_bounds__(512, 2) void fuse(
    int mode, int last,
    float* __restrict__ slots,
    const float* __restrict__ accp, const float* __restrict__ sump,
    const unsigned short* __restrict__ wgru,
    const unsigned short* __restrict__ wm1,
    const unsigned short* __restrict__ wm2,
    const unsigned short* __restrict__ wq_,
    unsigned short* __restrict__ qfg,
    const float* __restrict__ gbi, const float* __restrict__ gbh,
    const float* __restrict__ lnsg, const float* __restrict__ lnsb,
    const float* __restrict__ lnfg, const float* __restrict__ lnfb,
    const float* __restrict__ mb1, const float* __restrict__ mb2,
    float* __restrict__ outp)
{
  __shared__ unsigned short uimg[4096];   // [8 dc][64][8] A-frag image (reused 3x)
  __shared__ unsigned short himg[4096];
  __shared__ unsigned short h1img[8192];  // [16 dc][64][8]
  __shared__ float hpr[16][260];
  __shared__ float stats[16][2];
  __shared__ float rowsum[8];
  int tid = threadIdx.x, w = tid >> 6, L = tid & 63;
  int m16 = L & 15, q = L >> 4;
  int b = blockIdx.x;
  for (int i = tid; i < 4096; i += 512) { uimg[i] = 0; himg[i] = 0; }
  __syncthreads();
  float hh[2][4];

  if (mode == 1) {
    if (tid < 8) {
      float s = 0.f;
      for (int p = 0; p < 16; ++p) s += sump[((b << 4) + p)*8 + tid];
      rowsum[tid] = s;
    }
    __syncthreads();
    { // reduce 16 half-width partial pairs -> updates, pack A-frag images
      int s = tid >> 6, dp = (tid & 63) << 2;     // 4 floats/thread
      int hi = dp >> 7, dlo = dp & 127;
      const float* base = accp + (((size_t)(b << 5) + hi)*8 + s)*128 + dlo;
      f32x4 a0 = (f32x4){0.f,0.f,0.f,0.f};
      for (int p = 0; p < 16; ++p)
        a0 += *(const f32x4*)(base + (size_t)p * 2048);
      float inv = 1.f / rowsum[s];
      int dc = dp >> 5, lp = s + ((dp >> 3) & 3)*16, j0 = dp & 7;  // 0 or 4
      us4 pk;
#pragma unroll
      for (int j = 0; j < 4; ++j) pk[j] = f2bf(a0[j]*inv);
      *(us4*)&uimg[(dc*64 + lp)*8 + j0] = pk;
      f32x4 h0 = *(const f32x4*)(slots + ((b << 3) + s)*256 + dp);
      us4 pk2;
#pragma unroll
      for (int j = 0; j < 4; ++j) pk2[j] = f2bf(h0[j]);
      *(us4*)&himg[(dc*64 + lp)*8 + j0] = pk2;
    }
    __syncthreads();
    // GRU MFMA: wave w owns d-tiles 2w, 2w+1; gates r/z/n col-local per d
    f32x4 aI[2][3], aH[2][3];
#pragma unroll
    for (int i = 0; i < 2; ++i)
#pragma unroll
      for (int g = 0; g < 3; ++g) { aI[i][g] = (f32x4){0.f,0.f,0.f,0.f}; aH[i][g] = (f32x4){0.f,0.f,0.f,0.f}; }
#pragma unroll
    for (int dc = 0; dc < 8; ++dc) {
      short8 au = *(const short8*)(uimg + (dc*64 + L)*8);
      short8 ah = *(const short8*)(himg + (dc*64 + L)*8);
#pragma unroll
      for (int i = 0; i < 2; ++i) {
        int dt = (w << 1) + i;
#pragma unroll
        for (int g = 0; g < 3; ++g) {
          short8 bu = *(const short8*)(wgru + (((g*16 + dt)*8 + dc)*64 + L)*8);
          aI[i][g] = mfma16(au, bu, aI[i][g]);
          short8 bh = *(const short8*)(wgru + (((48 + g*16 + dt)*8 + dc)*64 + L)*8);
          aH[i][g] = mfma16(ah, bh, aH[i][g]);
        }
      }
    }
#pragma unroll
    for (int i = 0; i < 2; ++i) {
      int d = ((w << 1) + i)*16 + m16;
      float bir = gbi[d], biz = gbi[256+d], bin = gbi[512+d];
      float bhr = gbh[d], bhz = gbh[256+d], bhn = gbh[512+d];
#pragma unroll
      for (int r = 0; r < 4; ++r) {
        int s = (q << 2) + r;
        if (s < 8) {
          float ir = aI[i][0][r] + bir, iz = aI[i][1][r] + biz, in_ = aI[i][2][r] + bin;
          float hr = aH[i][0][r] + bhr, hz = aH[i][1][r] + bhz, hn = aH[i][2][r] + bhn;
          float rg = 1.f / (1.f + __expf(-(ir + hr)));
          float zg = 1.f / (1.f + __expf(-(iz + hz)));
          float nn = tanhf(in_ + rg * hn);
          float hv = slots[((b << 3) + s)*256 + d];
          float hp = (1.f - zg)*nn + zg*hv;
          hh[i][r] = hp;
          hpr[s][d] = hp;
        } else {
          hpr[s][d] = 0.f;
        }
      }
    }
    __syncthreads();
    ln_stats512(hpr, stats, tid);
    __syncthreads();
    { // LN_ff -> A image
      int s = tid >> 6, dp = (tid & 63) << 2;
      float mean = stats[s][0], rstd = stats[s][1];
      int dc = dp >> 5, lp = s + ((dp >> 3) & 3)*16, j0 = dp & 7;
      us4 pk;
#pragma unroll
      for (int j = 0; j < 4; ++j)
        pk[j] = f2bf((hpr[s][dp+j] - mean)*rstd*lnfg[dp+j] + lnfb[dp+j]);
      *(us4*)&uimg[(dc*64 + lp)*8 + j0] = pk;
    }
    __syncthreads();
    // MLP layer 1 (relu) -> h1 A-frag image; wave w owns 4 col-tiles
    f32x4 a1[4];
#pragma unroll
    for (int c = 0; c < 4; ++c) a1[c] = (f32x4){0.f,0.f,0.f,0.f};
#pragma unroll
    for (int dc = 0; dc < 8; ++dc) {
      short8 aa = *(const short8*)(uimg + (dc*64 + L)*8);
#pragma unroll
      for (int c = 0; c < 4; ++c) {
        short8 bb = *(const short8*)(wm1 + ((((w<<2)+c)*8 + dc)*64 + L)*8);
        a1[c] = mfma16(aa, bb, a1[c]);
      }
    }
#pragma unroll
    for (int c = 0; c < 4; ++c) {
      int col = ((w << 2) + c)*16 + m16;
      float bv = mb1[col];
      int dc2 = col >> 5, lpb = ((col >> 3) & 3)*16, j = col & 7;
#pragma unroll
      for (int r = 0; r < 4; ++r) {
        int s = (q << 2) + r;
        float v = (s < 8) ? fmaxf(a1[c][r] + bv, 0.f) : 0.f;
        h1img[(dc2*64 + s + lpb)*8 + j] = f2bf(v);
      }
    }
    __syncthreads();
    // MLP layer 2 + residual; wave's col tiles == its GRU d-tiles
    f32x4 a2[2];
#pragma unroll
    for (int i = 0; i < 2; ++i) a2[i] = (f32x4){0.f,0.f,0.f,0.f};
#pragma unroll
    for (int dc2 = 0; dc2 < 16; ++dc2) {
      short8 aa = *(const short8*)(h1img + (dc2*64 + L)*8);
#pragma unroll
      for (int i = 0; i < 2; ++i) {
        short8 bb = *(const short8*)(wm2 + ((((w<<1)+i)*16 + dc2)*64 + L)*8);
        a2[i] = mfma16(aa, bb, a2[i]);
      }
    }
#pragma unroll
    for (int i = 0; i < 2; ++i) {
      int d = ((w << 1) + i)*16 + m16;
      float b2v = mb2[d];
#pragma unroll
      for (int r = 0; r < 4; ++r) {
        int s = (q << 2) + r;
        if (s < 8) {
          float o = a2[i][r] + b2v + hh[i][r];
          slots[((b << 3) + s)*256 + d] = o;
          if (last) outp[((b << 3) + s)*256 + d] = o;
          hpr[s][d] = o;
        }
      }
    }
    __syncthreads();
  } else {
    int s = tid >> 6, dp = (tid & 63) << 2;
#pragma unroll
    for (int j = 0; j < 4; ++j) {
      hpr[s][dp+j] = slots[((b << 3) + s)*256 + dp + j];
      hpr[8 + s][dp+j] = 0.f;
    }
    __syncthreads();
  }

  // q for next attention pass: LN_slots -> @q_w -> B-frag-direct global image
  ln_stats512(hpr, stats, tid);
  __syncthreads();
  {
    int s = tid >> 6, dp = (tid & 63) << 2;
    float mean = stats[s][0], rstd = stats[s][1];
    int dc = dp >> 5, lp = s + ((dp >> 3) & 3)*16, j0 = dp & 7;
    us4 pk;
#pragma unroll
    for (int j = 0; j < 4; ++j)
      pk[j] = f2bf((hpr[s][dp+j] - mean)*rstd*lnsg[dp+j] + lnsb[dp+j]);
    *(us4*)&uimg[(dc*64 + lp)*8 + j0] = pk;
  }
  __syncthreads();
  {
    f32x4 aq[2];
#pragma unroll
    for (int i = 0; i < 2; ++i) aq[i] = (f32x4){0.f,0.f,0.f,0.f};
#pragma unroll
    for (int dc = 0; dc < 8; ++dc) {
      short8 aa = *(const short8*)(uimg + (dc*64 + L)*8);
#pragma unroll
      for (int i = 0; i < 2; ++i) {
        short8 bb = *(const short8*)(wq_ + ((((w<<1)+i)*8 + dc)*64 + L)*8);
        aq[i] = mfma16(aa, bb, aq[i]);
      }
    }
    unsigned short* qb = qfg + ((size_t)b << 12);
#pragma unroll
    for (int i = 0; i < 2; ++i) {
      int col = ((w << 1) + i)*16 + m16;
      int dc = col >> 5, lpb = ((col >> 3) & 3)*16, j = col & 7;
#pragma unroll
      for (int r = 0; r < 4; ++r) {
        int s = (q << 2) + r;
        qb[(dc*64 + s + lpb)*8 + j] = (s < 8) ? f2bf(aq[i][r]) : (unsigned short)0;
      }
    }
  }
}

// ---------------------------------------------------------------------------
extern "C" void kernel_launch(void* const* d_in, const int* in_sizes, int n_in,
                              void* d_out, int out_size, void* d_ws, size_t ws_size,
                              hipStream_t stream) {
  (void)in_sizes; (void)n_in; (void)out_size;
  if (ws_size < WS_NEED) return;   // workspace guard (need ~275 MB)

  const float* inputs    = (const float*)d_in[0];
  const float* slot_init = (const float*)d_in[1];
  const float* k_w       = (const float*)d_in[2];
  const float* q_w       = (const float*)d_in[3];
  const float* v_w       = (const float*)d_in[4];
  const float* gru_wi    = (const float*)d_in[5];
  const float* gru_wh    = (const float*)d_in[6];
  const float* gru_bi    = (const float*)d_in[7];
  const float* gru_bh    = (const float*)d_in[8];
  const float* ln_in_g   = (const float*)d_in[9];
  const float* ln_in_b   = (const float*)d_in[10];
  const float* ln_s_g    = (const float*)d_in[11];
  const float* ln_s_b    = (const float*)d_in[12];
  const float* ln_f_g    = (const float*)d_in[13];
  const float* ln_f_b    = (const float*)d_in[14];
  const float* m_w1      = (const float*)d_in[15];
  const float* m_b1      = (const float*)d_in[16];
  const float* m_w2      = (const float*)d_in[17];
  const float* m_b2      = (const float*)d_in[18];

  char* ws = (char*)d_ws;
  unsigned short* kfr  = (unsigned short*)(ws + O_KF);
  unsigned short* vfr  = (unsigned short*)(ws + O_VF);
  float*          accp = (float*)(ws + O_ACC);
  float*          sump = (float*)(ws + O_SUM);
  float*          slots= (float*)(ws + O_SL);
  unsigned short* qfg  = (unsigned short*)(ws + O_QF);
  unsigned short* wkv  = (unsigned short*)(ws + O_WKV);
  unsigned short* wq_  = (unsigned short*)(ws + O_WQ);
  unsigned short* wgru = (unsigned short*)(ws + O_WGRU);
  unsigned short* wm1  = (unsigned short*)(ws + O_WM1);
  unsigned short* wm2  = (unsigned short*)(ws + O_WM2);

  prepack<<<544, 256, 0, stream>>>(k_w, q_w, v_w, gru_wi, gru_wh, m_w1, m_w2,
                                   slot_init, wkv, wq_, wgru, wm1, wm2, slots);
  gemm_kv<<<4096, 512, 0, stream>>>(inputs, ln_in_g, ln_in_b, wkv, kfr, vfr);
  fuse<<<64, 512, 0, stream>>>(0, 0, slots, accp, sump, wgru, wm1, wm2, wq_, qfg,
                               gru_bi, gru_bh, ln_s_g, ln_s_b, ln_f_g, ln_f_b,
                               m_b1, m_b2, (float*)d_out);
  for (int it = 0; it < 3; ++it) {
    attn<<<dim3(32, 64), 256, 0, stream>>>(kfr, vfr, qfg, accp, sump);
    fuse<<<64, 512, 0, stream>>>(1, (it == 2) ? 1 : 0, slots, accp, sump, wgru,
                                 wm1, wm2, wq_, qfg, gru_bi, gru_bh, ln_s_g,
                                 ln_s_b, ln_f_g, ln_f_b, m_b1, m_b2,
                                 (float*)d_out);
  }
}

// Round 5
// 836.868 us; speedup vs baseline: 1.0791x; 1.0791x over previous
//
#include <hip/hip_runtime.h>
#include <cstdint>
#include <cstddef>

// ---------------------------------------------------------------------------
// SlotAttention on MI355X.
//  (1) prepack: bf16 weight images in MFMA B-fragment order; slot_init copy.
//  (2) gemm_kv: x=LN(inputs); [k|v] = x @ [k_w/16 | v_w] via bf16 MFMA.
//      64-token blocks, 512 thr (8 waves), acc[4][4], concurrent K+V scatter.
//  (3) attn R8: R3 structure (full D, same bytes — R4 proved attn is
//      effective-BW-bound at ~2.3 TB/s, so no traffic added), occupancy
//      raised 12->16 waves/CU: qf in LDS (-32 VGPR), vfA prestage 4 (-16),
//      wave-PAIR reduction (red 16.6 KB not 33), 32 partials/batch direct
//      to global, launch_bounds(256,4). LDS 25 KB -> 4 blocks/CU.
//  (4) fuse: 512 thr (8 waves); reduce over 32 partials (was 16).
// ---------------------------------------------------------------------------

typedef __attribute__((ext_vector_type(8))) short short8;
typedef __attribute__((ext_vector_type(4))) float f32x4;
typedef __attribute__((ext_vector_type(4))) unsigned short us4;
typedef __attribute__((ext_vector_type(8))) unsigned short us8;

#define DEV static __device__ __forceinline__

DEV unsigned short f2bf(float f) {
  union { float f; unsigned int u; } v; v.f = f;
  unsigned int r = v.u + 0x7FFFu + ((v.u >> 16) & 1u);
  return (unsigned short)(r >> 16);
}

DEV f32x4 mfma16(short8 a, short8 b, f32x4 c) {
  return __builtin_amdgcn_mfma_f32_16x16x32_bf16(a, b, c, 0, 0, 0);
}

// ---------------- workspace layout (bytes) ----------------
constexpr size_t O_KF   = 0;                                  // k frags: [64][256 tb][8 dc][64 chunk(pi)][8] bf16
constexpr size_t SZ_KF  = (size_t)64*256*8*64*8*2;            // 128 MB
constexpr size_t O_VF   = O_KF + SZ_KF;                       // v frags: [64][128 c32][16 dt][64][8] bf16
constexpr size_t SZ_VF  = (size_t)64*128*16*64*8*2;           // 128 MB
constexpr size_t O_ACC  = O_VF + SZ_VF;                       // [64][32 part][8 s][256 d] f32 = 16 MB
constexpr size_t SZ_ACC = (size_t)64*32*8*256*4;              // 16 MB
constexpr size_t O_SUM  = O_ACC + SZ_ACC;                     // [64][32][8] f32
constexpr size_t SZ_SUM = (size_t)64*32*8*4;
constexpr size_t O_SL   = O_SUM + SZ_SUM;                     // slots [64][8][256] f32
constexpr size_t SZ_SL  = (size_t)64*8*256*4;
constexpr size_t O_QF   = O_SL + SZ_SL;                       // q frags [64][8 dc][64][8] bf16
constexpr size_t SZ_QF  = (size_t)64*8*64*8*2;
constexpr size_t O_WKV  = O_QF + SZ_QF;                       // [32 ct][8 dc][64][8]
constexpr size_t SZ_WKV = (size_t)32*8*64*8*2;
constexpr size_t O_WQ   = O_WKV + SZ_WKV;                     // [16][8][64][8]
constexpr size_t SZ_WQ  = (size_t)16*8*64*8*2;
constexpr size_t O_WGRU = O_WQ + SZ_WQ;                       // [96][8][64][8] (wi:0-47, wh:48-95)
constexpr size_t SZ_WGRU= (size_t)96*8*64*8*2;
constexpr size_t O_WM1  = O_WGRU + SZ_WGRU;                   // [32][8][64][8]
constexpr size_t SZ_WM1 = (size_t)32*8*64*8*2;
constexpr size_t O_WM2  = O_WM1 + SZ_WM1;                     // [16][16][64][8]
constexpr size_t SZ_WM2 = (size_t)16*16*64*8*2;
constexpr size_t WS_NEED= O_WM2 + SZ_WM2;                     // ~275 MB

// ---------------------------------------------------------------------------
// prepack: weight fragment images + slots init. 544 blocks x 256.
// B-frag convention: lane L holds W[k = dc*32 + (L>>4)*8 + j][col = ct*16 + (L&15)]
// ---------------------------------------------------------------------------
__global__ void prepack(
    const float* __restrict__ kw, const float* __restrict__ qw,
    const float* __restrict__ vw, const float* __restrict__ wi,
    const float* __restrict__ wh, const float* __restrict__ w1,
    const float* __restrict__ w2, const float* __restrict__ slot_init,
    unsigned short* __restrict__ wkv, unsigned short* __restrict__ wq_,
    unsigned short* __restrict__ wgru, unsigned short* __restrict__ wm1,
    unsigned short* __restrict__ wm2, float* __restrict__ slots)
{
  int idx = blockIdx.x * 256 + threadIdx.x;
  if (idx < 16384) {                                    // kv: [32][8][64]
    int ct = idx >> 9, dc = (idx >> 6) & 7, L = idx & 63;
    int col = ct*16 + (L & 15), k0 = dc*32 + ((L>>4)*8);
    if (col < 256) {
      for (int j = 0; j < 8; ++j) wkv[idx*8+j] = f2bf(kw[(size_t)(k0+j)*256 + col] * 0.0625f);
    } else {
      int c = col - 256;
      for (int j = 0; j < 8; ++j) wkv[idx*8+j] = f2bf(vw[(size_t)(k0+j)*256 + c]);
    }
  } else if (idx < 24576) {                             // q: [16][8][64]
    int t = idx - 16384;
    int ct = t >> 9, dc = (t >> 6) & 7, L = t & 63;
    int col = ct*16 + (L & 15), k0 = dc*32 + ((L>>4)*8);
    for (int j = 0; j < 8; ++j) wq_[t*8+j] = f2bf(qw[(size_t)(k0+j)*256 + col]);
  } else if (idx < 73728) {                             // gru: [96][8][64]
    int t = idx - 24576;
    int ct = t >> 9, dc = (t >> 6) & 7, L = t & 63;
    int k0 = dc*32 + ((L>>4)*8);
    const float* W = (ct < 48) ? wi : wh;
    int col = ((ct < 48) ? ct : (ct - 48))*16 + (L & 15);
    for (int j = 0; j < 8; ++j) wgru[t*8+j] = f2bf(W[(size_t)(k0+j)*768 + col]);
  } else if (idx < 90112) {                             // mlp1: [32][8][64]
    int t = idx - 73728;
    int ct = t >> 9, dc = (t >> 6) & 7, L = t & 63;
    int col = ct*16 + (L & 15), k0 = dc*32 + ((L>>4)*8);
    for (int j = 0; j < 8; ++j) wm1[t*8+j] = f2bf(w1[(size_t)(k0+j)*512 + col]);
  } else if (idx < 106496) {                            // mlp2: [16][16][64]
    int t = idx - 90112;
    int ct = t >> 10, dc = (t >> 6) & 15, L = t & 63;
    int col = ct*16 + (L & 15), k0 = dc*32 + ((L>>4)*8);
    for (int j = 0; j < 8; ++j) wm2[t*8+j] = f2bf(w2[(size_t)(k0+j)*256 + col]);
  } else {                                              // slots copy (float4)
    int t = idx - 106496;
    f32x4 v = *(const f32x4*)(slot_init + (size_t)t*4);
    *(f32x4*)(slots + (size_t)t*4) = v;
  }
}

// ---------------------------------------------------------------------------
// gemm_kv: 4096 blocks x 512 thr. Block = 64 tokens x all 512 out cols.
// Wave w owns ct = 4w..4w+3 (64 cols) across 4 token tiles: acc[4][4] = 64
// AGPR (16 waves/CU reg cap), each B-frag load feeds 4 MFMAs.
// Phases: LN-stage | MFMA | concurrent K+V scatter | coalesced store.
// K image chunk permutation: pi = o1*32 | r*8 | o0*4 | q  (conflict-free)
// ---------------------------------------------------------------------------
__global__ __launch_bounds__(512, 4) void gemm_kv(
    const float* __restrict__ x, const float* __restrict__ lng,
    const float* __restrict__ lnb, const unsigned short* __restrict__ wkv,
    unsigned short* __restrict__ kfr, unsigned short* __restrict__ vfr)
{
  // 64 KB: A-tile 64x264 shorts (33.8 KB), then reused as
  //        K img shorts [0,16384) + V img shorts [16384,32768)
  __shared__ unsigned short smem[32768];
  int tid = threadIdx.x, w = tid >> 6, L = tid & 63;
  int m16 = L & 15, q = L >> 4;
  int blk = blockIdx.x;
  int b = blk >> 6;
  int n0 = (blk & 63) << 6;

  { // fused LN + stage bf16 A tile. wave w: rows w*8..w*8+7; 8 thr/row
    int r = (w << 3) + (L & 7), t8 = L >> 3;
    const float* xr = x + ((size_t)((b << 12) + n0 + r) << 8) + (t8 << 5);
    float xv[32];
    float s = 0.f, s2 = 0.f;
#pragma unroll
    for (int i = 0; i < 8; ++i) {
      f32x4 v = *(const f32x4*)(xr + (i << 2));
#pragma unroll
      for (int jj = 0; jj < 4; ++jj) { float t = v[jj]; xv[i*4+jj] = t; s += t; s2 += t*t; }
    }
    s  += __shfl_xor(s, 8);  s  += __shfl_xor(s, 16);  s  += __shfl_xor(s, 32);
    s2 += __shfl_xor(s2, 8); s2 += __shfl_xor(s2, 16); s2 += __shfl_xor(s2, 32);
    float mean = s * 0.00390625f;
    float var  = s2 * 0.00390625f - mean * mean;
    float rstd = rsqrtf(fmaxf(var, 0.f) + 1e-5f);
    unsigned short* arow = smem + r * 264 + (t8 << 5);
    const float* gg = lng + (t8 << 5);
    const float* bb = lnb + (t8 << 5);
#pragma unroll
    for (int i = 0; i < 4; ++i) {
      f32x4 g0 = *(const f32x4*)(gg + (i << 3));
      f32x4 g1 = *(const f32x4*)(gg + (i << 3) + 4);
      f32x4 b0 = *(const f32x4*)(bb + (i << 3));
      f32x4 b1 = *(const f32x4*)(bb + (i << 3) + 4);
      us8 pk;
#pragma unroll
      for (int jj = 0; jj < 4; ++jj) {
        pk[jj]     = f2bf((xv[i*8+jj]   - mean) * rstd * g0[jj] + b0[jj]);
        pk[4 + jj] = f2bf((xv[i*8+4+jj] - mean) * rstd * g1[jj] + b1[jj]);
      }
      *(us8*)(arow + (i << 3)) = pk;
    }
  }
  __syncthreads();

  f32x4 acc[4][4];
#pragma unroll
  for (int mt = 0; mt < 4; ++mt)
#pragma unroll
    for (int c = 0; c < 4; ++c) acc[mt][c] = (f32x4){0.f,0.f,0.f,0.f};

#pragma unroll
  for (int dc = 0; dc < 8; ++dc) {
    short8 af[4];
#pragma unroll
    for (int mt = 0; mt < 4; ++mt)
      af[mt] = *(const short8*)(smem + ((mt << 4) + m16) * 264 + dc*32 + q*8);
#pragma unroll
    for (int c = 0; c < 4; ++c) {
      short8 bf = *(const short8*)(wkv + ((((w<<2)+c)*8 + dc)*64 + L) * 8);
#pragma unroll
      for (int mt = 0; mt < 4; ++mt)
        acc[mt][c] = mfma16(af[mt], bf, acc[mt][c]);
    }
  }
  __syncthreads();   // A-tile dead; reuse smem for both images

  if (w < 4) {          // K image: cols 0..255, chunk pos = pi(oct,r,q)
#pragma unroll
    for (int mt = 0; mt < 4; ++mt)
#pragma unroll
      for (int c = 0; c < 4; ++c) {
        int col = (w << 6) + (c << 4) + m16;
        int dc = col >> 5, oct = (col >> 3) & 3, j = col & 7;
        int base = ((mt << 3) + dc)*64 + ((oct >> 1) << 5) + ((oct & 1) << 2) + q;
#pragma unroll
        for (int r = 0; r < 4; ++r)
          smem[(base + (r << 3))*8 + j] = f2bf(acc[mt][c][r]);
      }
  } else {              // V image: cols 256..511 -> d-major (transposed) A-frag
#pragma unroll
    for (int mt = 0; mt < 4; ++mt)
#pragma unroll
      for (int c = 0; c < 4; ++c) {
        int d = ((w - 4) << 6) + (c << 4) + m16;
        int dt = d >> 4;
        int tok = ((mt & 1) << 4) + (q << 2);
        int lp = m16 + ((tok >> 3) << 4), j0 = (q & 1) << 2;
        us4 pk;
#pragma unroll
        for (int r = 0; r < 4; ++r) pk[r] = f2bf(acc[mt][c][r]);
        *(us4*)&smem[16384 + ((mt >> 1) << 13) + ((dt << 6) + lp)*8 + j0] = pk;
      }
  }
  __syncthreads();
  { // store K image (coalesced, 2048 us8)
    size_t kb = (size_t)b*256 + ((blk & 63) << 2);
#pragma unroll
    for (int ii = 0; ii < 4; ++ii) {
      int cix = ii*512 + tid;
      int rt = cix >> 9, dcs = (cix >> 6) & 7, p = cix & 63;
      short8 vv = *(const short8*)(smem + (size_t)cix*8);
      *(short8*)(kfr + (((kb + rt)*8 + dcs)*64 + p)*8) = vv;
    }
    // store V image (coalesced, 2048 us8)
    size_t vb = (size_t)b*128 + ((blk & 63) << 1);
#pragma unroll
    for (int ii = 0; ii < 4; ++ii) {
      int cix = ii*512 + tid;
      int cc = cix >> 10, dt = (cix >> 6) & 15, lp = cix & 63;
      short8 vv = *(const short8*)(smem + 16384 + (size_t)cix*8);
      *(short8*)(vfr + (((vb + cc)*16 + dt)*64 + lp)*8) = vv;
    }
  }
}

// ---------------------------------------------------------------------------
// attn R8: grid (16, 64) x 256, full D per wave (R3 structure, same bytes).
// Occupancy: qf in LDS, vfA prestage 4, wave-pair reduction, 32 partials
// straight to global, launch_bounds(256,4), LDS 25 KB -> 4 blocks/CU.
// K chunks at pi-permuted positions -> base-pointer offset pk*8.
// ---------------------------------------------------------------------------
__global__ __launch_bounds__(256, 4) void attn(
    const unsigned short* __restrict__ kfr,
    const unsigned short* __restrict__ vfr,
    const unsigned short* __restrict__ qfg,
    float* __restrict__ accp, float* __restrict__ sump)
{
  __shared__ float red[2][8][260];        // odd wave of each pair parks here
  __shared__ float rsum[2][8];
  __shared__ unsigned short qlds[4096];   // 8 KB: [8 dc][64][8]
  int tid = threadIdx.x, w = tid >> 6, L = tid & 63;
  int slot = L & 15, q = L >> 4;
  int bt = blockIdx.x, b = blockIdx.y;
  int wv = (bt << 2) + w;
  int pk = (L & 32) | ((L & 3) << 3) | ((L & 16) >> 2) | ((L >> 2) & 3);
  const unsigned short* kb = kfr + ((size_t)b << 20) + pk*8;
  const unsigned short* vbp = vfr + ((size_t)b << 20) + L*8;

  { // stage q fragments (8 KB) once per block
    const unsigned short* qg = qfg + ((size_t)b << 12);
    *(us8*)&qlds[tid*8]        = *(const us8*)(qg + tid*8);
    *(us8*)&qlds[(tid+256)*8]  = *(const us8*)(qg + (tid+256)*8);
  }
  __syncthreads();

  f32x4 accU[16];
#pragma unroll
  for (int dt = 0; dt < 16; ++dt) accU[dt] = (f32x4){0.f,0.f,0.f,0.f};
  float rs = 0.f;

  for (int c = 0; c < 2; ++c) {
    int tb0 = (wv << 2) + (c << 1);
    int c32 = (wv << 1) + c;
    const unsigned short* kt = kb + (size_t)tb0 * 4096;
    const unsigned short* vt = vbp + (size_t)c32 * 8192;
    short8 vfA[4];
#pragma unroll
    for (int dt = 0; dt < 4; ++dt)
      vfA[dt] = *(const short8*)(vt + dt*512);
    f32x4 d0 = (f32x4){0.f,0.f,0.f,0.f}, d1 = (f32x4){0.f,0.f,0.f,0.f};
#pragma unroll
    for (int dc = 0; dc < 8; ++dc) {
      short8 k0 = *(const short8*)(kt + dc*512);
      short8 k1 = *(const short8*)(kt + 4096 + dc*512);
      short8 qf = *(const short8*)(qlds + (dc*64 + L)*8);
      d0 = mfma16(k0, qf, d0);
      d1 = mfma16(k1, qf, d1);
    }
    // softmax over 8 slots (dots are O(1): skip max-subtract), +eps
    float p0[4], p1[4];
#pragma unroll
    for (int r = 0; r < 4; ++r) {
      float e = __expf(d0[r]);
      float ss = e;
      ss += __shfl_xor(ss, 1); ss += __shfl_xor(ss, 2); ss += __shfl_xor(ss, 4);
      float pv = (slot < 8) ? (e / ss + 1e-6f) : 0.f;
      rs += pv; p0[r] = pv;
    }
#pragma unroll
    for (int r = 0; r < 4; ++r) {
      float e = __expf(d1[r]);
      float ss = e;
      ss += __shfl_xor(ss, 1); ss += __shfl_xor(ss, 2); ss += __shfl_xor(ss, 4);
      float pv = (slot < 8) ? (e / ss + 1e-6f) : 0.f;
      rs += pv; p1[r] = pv;
    }
    // in-wave transform to B-frag: pb[j] = P[token 8q+j][slot m16]
    short8 pb;
#pragma unroll
    for (int j = 0; j < 8; ++j) {
      int srcl = slot + ((q & 1) << 5) + ((j >> 2) << 4);
      float va = __shfl(p0[j & 3], srcl);
      float vb2 = __shfl(p1[j & 3], srcl);
      pb[j] = (short)f2bf((q >> 1) ? vb2 : va);
    }
#pragma unroll
    for (int dt = 0; dt < 4; ++dt) accU[dt] = mfma16(vfA[dt], pb, accU[dt]);
#pragma unroll
    for (int dt = 4; dt < 16; ++dt) {
      short8 vv = *(const short8*)(vt + dt*512);
      accU[dt] = mfma16(vv, pb, accU[dt]);
    }
  }
  rs += __shfl_xor(rs, 16);
  rs += __shfl_xor(rs, 32);

  // wave-pair reduction: odd wave parks in LDS; even wave adds + stores
  if (w & 1) {
    if (slot < 8) {
#pragma unroll
      for (int dt = 0; dt < 16; ++dt)
        *(f32x4*)&red[w >> 1][slot][dt*16 + (q << 2)] = accU[dt];
    }
    if (L < 8) rsum[w >> 1][L] = rs;
  }
  __syncthreads();
  if (!(w & 1)) {
    int pr = (bt << 1) + (w >> 1);              // partial index 0..31
    if (slot < 8) {
      float* ab = accp + (((size_t)(b << 5) + pr)*8 + slot)*256;
#pragma unroll
      for (int dt = 0; dt < 16; ++dt) {
        f32x4 v = accU[dt] + *(const f32x4*)&red[w >> 1][slot][dt*16 + (q << 2)];
        *(f32x4*)(ab + dt*16 + (q << 2)) = v;
      }
    }
    if (L < 8)
      sump[((size_t)(b << 5) + pr)*8 + L] = rs + rsum[w >> 1][L];
  }
}

// ---------------------------------------------------------------------------
// fuse: 64 blocks x 512 thr (8 waves, 2 waves/SIMD). mode1: reduce 32
// partials -> updates -> GRU -> LN -> MLP -> residual -> slots (+out).
// Always: pack next-iter q.
// ---------------------------------------------------------------------------
DEV void ln_stats512(const float hpr[16][260], float stats[16][2], int tid) {
  int row = tid >> 5, seg = tid & 31;    // 512 thr = 16 rows x 32 segs x 8 el
  float s = 0.f, s2 = 0.f;
#pragma unroll
  for (int jj = 0; jj < 8; ++jj) { float v = hpr[row][seg*8 + jj]; s += v; s2 += v*v; }
  s  += __shfl_xor(s, 1);  s  += __shfl_xor(s, 2);  s  += __shfl_xor(s, 4);
  s  += __shfl_xor(s, 8);  s  += __shfl_xor(s, 16);
  s2 += __shfl_xor(s2, 1); s2 += __shfl_xor(s2, 2); s2 += __shfl_xor(s2, 4);
  s2 += __shfl_xor(s2, 8); s2 += __shfl_xor(s2, 16);
  if (seg == 0) {
    float mean = s * 0.00390625f;
    float var  = s2 * 0.00390625f - mean*mean;
    stats[row][0] = mean;
    stats[row][1] = rsqrtf(fmaxf(var, 0.f) + 1e-5f);
  }
}

__global__ __launch_bounds__(512, 2) void fuse(
    int mode, int last,
    float* __restrict__ slots,
    const float* __restrict__ accp, const float* __restrict__ sump,
    const unsigned short* __restrict__ wgru,
    const unsigned short* __restrict__ wm1,
    const unsigned short* __restrict__ wm2,
    const unsigned short* __restrict__ wq_,
    unsigned short* __restrict__ qfg,
    const float* __restrict__ gbi, const float* __restrict__ gbh,
    const float* __restrict__ lnsg, const float* __restrict__ lnsb,
    const float* __restrict__ lnfg, const float* __restrict__ lnfb,
    const float* __restrict__ mb1, const float* __restrict__ mb2,
    float* __restrict__ outp)
{
  __shared__ unsigned short uimg[4096];   // [8 dc][64][8] A-frag image (reused 3x)
  __shared__ unsigned short himg[4096];
  __shared__ unsigned short h1img[8192];  // [16 dc][64][8]
  __shared__ float hpr[16][260];
  __shared__ float stats[16][2];
  __shared__ float rowsum[8];
  int tid = threadIdx.x, w = tid >> 6, L = tid & 63;
  int m16 = L & 15, q = L >> 4;
  int b = blockIdx.x;
  for (int i = tid; i < 4096; i += 512) { uimg[i] = 0; himg[i] = 0; }
  __syncthreads();
  float hh[2][4];

  if (mode == 1) {
    if (tid < 8) {
      float s = 0.f;
      for (int p = 0; p < 32; ++p) s += sump[((size_t)(b << 5) + p)*8 + tid];
      rowsum[tid] = s;
    }
    __syncthreads();
    { // reduce 32 partials -> updates, pack A-frag images (updates + prev)
      int s = tid >> 6, dp = (tid & 63) << 2;     // 4 floats/thread
      const float* base = accp + (((size_t)(b << 5)*8 + s) << 8) + dp;
      f32x4 a0 = (f32x4){0.f,0.f,0.f,0.f};
      for (int p = 0; p < 32; ++p)
        a0 += *(const f32x4*)(base + (size_t)p * 2048);
      float inv = 1.f / rowsum[s];
      int dc = dp >> 5, lp = s + ((dp >> 3) & 3)*16, j0 = dp & 7;  // 0 or 4
      us4 pk;
#pragma unroll
      for (int j = 0; j < 4; ++j) pk[j] = f2bf(a0[j]*inv);
      *(us4*)&uimg[(dc*64 + lp)*8 + j0] = pk;
      f32x4 h0 = *(const f32x4*)(slots + ((b << 3) + s)*256 + dp);
      us4 pk2;
#pragma unroll
      for (int j = 0; j < 4; ++j) pk2[j] = f2bf(h0[j]);
      *(us4*)&himg[(dc*64 + lp)*8 + j0] = pk2;
    }
    __syncthreads();
    // GRU MFMA: wave w owns d-tiles 2w, 2w+1; gates r/z/n col-local per d
    f32x4 aI[2][3], aH[2][3];
#pragma unroll
    for (int i = 0; i < 2; ++i)
#pragma unroll
      for (int g = 0; g < 3; ++g) { aI[i][g] = (f32x4){0.f,0.f,0.f,0.f}; aH[i][g] = (f32x4){0.f,0.f,0.f,0.f}; }
#pragma unroll
    for (int dc = 0; dc < 8; ++dc) {
      short8 au = *(const short8*)(uimg + (dc*64 + L)*8);
      short8 ah = *(const short8*)(himg + (dc*64 + L)*8);
#pragma unroll
      for (int i = 0; i < 2; ++i) {
        int dt = (w << 1) + i;
#pragma unroll
        for (int g = 0; g < 3; ++g) {
          short8 bu = *(const short8*)(wgru + (((g*16 + dt)*8 + dc)*64 + L)*8);
          aI[i][g] = mfma16(au, bu, aI[i][g]);
          short8 bh = *(const short8*)(wgru + (((48 + g*16 + dt)*8 + dc)*64 + L)*8);
          aH[i][g] = mfma16(ah, bh, aH[i][g]);
        }
      }
    }
#pragma unroll
    for (int i = 0; i < 2; ++i) {
      int d = ((w << 1) + i)*16 + m16;
      float bir = gbi[d], biz = gbi[256+d], bin = gbi[512+d];
      float bhr = gbh[d], bhz = gbh[256+d], bhn = gbh[512+d];
#pragma unroll
      for (int r = 0; r < 4; ++r) {
        int s = (q << 2) + r;
        if (s < 8) {
          float ir = aI[i][0][r] + bir, iz = aI[i][1][r] + biz, in_ = aI[i][2][r] + bin;
          float hr = aH[i][0][r] + bhr, hz = aH[i][1][r] + bhz, hn = aH[i][2][r] + bhn;
          float rg = 1.f / (1.f + __expf(-(ir + hr)));
          float zg = 1.f / (1.f + __expf(-(iz + hz)));
          float nn = tanhf(in_ + rg * hn);
          float hv = slots[((b << 3) + s)*256 + d];
          float hp = (1.f - zg)*nn + zg*hv;
          hh[i][r] = hp;
          hpr[s][d] = hp;
        } else {
          hpr[s][d] = 0.f;
        }
      }
    }
    __syncthreads();
    ln_stats512(hpr, stats, tid);
    __syncthreads();
    { // LN_ff -> A image
      int s = tid >> 6, dp = (tid & 63) << 2;
      float mean = stats[s][0], rstd = stats[s][1];
      int dc = dp >> 5, lp = s + ((dp >> 3) & 3)*16, j0 = dp & 7;
      us4 pk;
#pragma unroll
      for (int j = 0; j < 4; ++j)
        pk[j] = f2bf((hpr[s][dp+j] - mean)*rstd*lnfg[dp+j] + lnfb[dp+j]);
      *(us4*)&uimg[(dc*64 + lp)*8 + j0] = pk;
    }
    __syncthreads();
    // MLP layer 1 (relu) -> h1 A-frag image; wave w owns 4 col-tiles
    f32x4 a1[4];
#pragma unroll
    for (int c = 0; c < 4; ++c) a1[c] = (f32x4){0.f,0.f,0.f,0.f};
#pragma unroll
    for (int dc = 0; dc < 8; ++dc) {
      short8 aa = *(const short8*)(uimg + (dc*64 + L)*8);
#pragma unroll
      for (int c = 0; c < 4; ++c) {
        short8 bb = *(const short8*)(wm1 + ((((w<<2)+c)*8 + dc)*64 + L)*8);
        a1[c] = mfma16(aa, bb, a1[c]);
      }
    }
#pragma unroll
    for (int c = 0; c < 4; ++c) {
      int col = ((w << 2) + c)*16 + m16;
      float bv = mb1[col];
      int dc2 = col >> 5, lpb = ((col >> 3) & 3)*16, j = col & 7;
#pragma unroll
      for (int r = 0; r < 4; ++r) {
        int s = (q << 2) + r;
        float v = (s < 8) ? fmaxf(a1[c][r] + bv, 0.f) : 0.f;
        h1img[(dc2*64 + s + lpb)*8 + j] = f2bf(v);
      }
    }
    __syncthreads();
    // MLP layer 2 + residual; wave's col tiles == its GRU d-tiles
    f32x4 a2[2];
#pragma unroll
    for (int i = 0; i < 2; ++i) a2[i] = (f32x4){0.f,0.f,0.f,0.f};
#pragma unroll
    for (int dc2 = 0; dc2 < 16; ++dc2) {
      short8 aa = *(const short8*)(h1img + (dc2*64 + L)*8);
#pragma unroll
      for (int i = 0; i < 2; ++i) {
        short8 bb = *(const short8*)(wm2 + ((((w<<1)+i)*16 + dc2)*64 + L)*8);
        a2[i] = mfma16(aa, bb, a2[i]);
      }
    }
#pragma unroll
    for (int i = 0; i < 2; ++i) {
      int d = ((w << 1) + i)*16 + m16;
      float b2v = mb2[d];
#pragma unroll
      for (int r = 0; r < 4; ++r) {
        int s = (q << 2) + r;
        if (s < 8) {
          float o = a2[i][r] + b2v + hh[i][r];
          slots[((b << 3) + s)*256 + d] = o;
          if (last) outp[((b << 3) + s)*256 + d] = o;
          hpr[s][d] = o;
        }
      }
    }
    __syncthreads();
  } else {
    int s = tid >> 6, dp = (tid & 63) << 2;
#pragma unroll
    for (int j = 0; j < 4; ++j) {
      hpr[s][dp+j] = slots[((b << 3) + s)*256 + dp + j];
      hpr[8 + s][dp+j] = 0.f;
    }
    __syncthreads();
  }

  // q for next attention pass: LN_slots -> @q_w -> B-frag-direct global image
  ln_stats512(hpr, stats, tid);
  __syncthreads();
  {
    int s = tid >> 6, dp = (tid & 63) << 2;
    float mean = stats[s][0], rstd = stats[s][1];
    int dc = dp >> 5, lp = s + ((dp >> 3) & 3)*16, j0 = dp & 7;
    us4 pk;
#pragma unroll
    for (int j = 0; j < 4; ++j)
      pk[j] = f2bf((hpr[s][dp+j] - mean)*rstd*lnsg[dp+j] + lnsb[dp+j]);
    *(us4*)&uimg[(dc*64 + lp)*8 + j0] = pk;
  }
  __syncthreads();
  {
    f32x4 aq[2];
#pragma unroll
    for (int i = 0; i < 2; ++i) aq[i] = (f32x4){0.f,0.f,0.f,0.f};
#pragma unroll
    for (int dc = 0; dc < 8; ++dc) {
      short8 aa = *(const short8*)(uimg + (dc*64 + L)*8);
#pragma unroll
      for (int i = 0; i < 2; ++i) {
        short8 bb = *(const short8*)(wq_ + ((((w<<1)+i)*8 + dc)*64 + L)*8);
        aq[i] = mfma16(aa, bb, aq[i]);
      }
    }
    unsigned short* qb = qfg + ((size_t)b << 12);
#pragma unroll
    for (int i = 0; i < 2; ++i) {
      int col = ((w << 1) + i)*16 + m16;
      int dc = col >> 5, lpb = ((col >> 3) & 3)*16, j = col & 7;
#pragma unroll
      for (int r = 0; r < 4; ++r) {
        int s = (q << 2) + r;
        qb[(dc*64 + s + lpb)*8 + j] = (s < 8) ? f2bf(aq[i][r]) : (unsigned short)0;
      }
    }
  }
}

// ---------------------------------------------------------------------------
extern "C" void kernel_launch(void* const* d_in, const int* in_sizes, int n_in,
                              void* d_out, int out_size, void* d_ws, size_t ws_size,
                              hipStream_t stream) {
  (void)in_sizes; (void)n_in; (void)out_size;
  if (ws_size < WS_NEED) return;   // workspace guard (need ~275 MB)

  const float* inputs    = (const float*)d_in[0];
  const float* slot_init = (const float*)d_in[1];
  const float* k_w       = (const float*)d_in[2];
  const float* q_w       = (const float*)d_in[3];
  const float* v_w       = (const float*)d_in[4];
  const float* gru_wi    = (const float*)d_in[5];
  const float* gru_wh    = (const float*)d_in[6];
  const float* gru_bi    = (const float*)d_in[7];
  const float* gru_bh    = (const float*)d_in[8];
  const float* ln_in_g   = (const float*)d_in[9];
  const float* ln_in_b   = (const float*)d_in[10];
  const float* ln_s_g    = (const float*)d_in[11];
  const float* ln_s_b    = (const float*)d_in[12];
  const float* ln_f_g    = (const float*)d_in[13];
  const float* ln_f_b    = (const float*)d_in[14];
  const float* m_w1      = (const float*)d_in[15];
  const float* m_b1      = (const float*)d_in[16];
  const float* m_w2      = (const float*)d_in[17];
  const float* m_b2      = (const float*)d_in[18];

  char* ws = (char*)d_ws;
  unsigned short* kfr  = (unsigned short*)(ws + O_KF);
  unsigned short* vfr  = (unsigned short*)(ws + O_VF);
  float*          accp = (float*)(ws + O_ACC);
  float*          sump = (float*)(ws + O_SUM);
  float*          slots= (float*)(ws + O_SL);
  unsigned short* qfg  = (unsigned short*)(ws + O_QF);
  unsigned short* wkv  = (unsigned short*)(ws + O_WKV);
  unsigned short* wq_  = (unsigned short*)(ws + O_WQ);
  unsigned short* wgru = (unsigned short*)(ws + O_WGRU);
  unsigned short* wm1  = (unsigned short*)(ws + O_WM1);
  unsigned short* wm2  = (unsigned short*)(ws + O_WM2);

  prepack<<<544, 256, 0, stream>>>(k_w, q_w, v_w, gru_wi, gru_wh, m_w1, m_w2,
                                   slot_init, wkv, wq_, wgru, wm1, wm2, slots);
  gemm_kv<<<4096, 512, 0, stream>>>(inputs, ln_in_g, ln_in_b, wkv, kfr, vfr);
  fuse<<<64, 512, 0, stream>>>(0, 0, slots, accp, sump, wgru, wm1, wm2, wq_, qfg,
                               gru_bi, gru_bh, ln_s_g, ln_s_b, ln_f_g, ln_f_b,
                               m_b1, m_b2, (float*)d_out);
  for (int it = 0; it < 3; ++it) {
    attn<<<dim3(16, 64), 256, 0, stream>>>(kfr, vfr, qfg, accp, sump);
    fuse<<<64, 512, 0, stream>>>(1, (it == 2) ? 1 : 0, slots, accp, sump, wgru,
                                 wm1, wm2, wq_, qfg, gru_bi, gru_bh, ln_s_g,
                                 ln_s_b, ln_f_g, ln_f_b, m_b1, m_b2,
                                 (float*)d_out);
  }
}